// Round 10
// baseline (137.955 us; speedup 1.0000x reference)
//
#include <hip/hip_runtime.h>
#include <cfloat>
#include <cmath>

#define N_NODES 20000
#define MAXD 32
#define F 128
#define NODES_PER_BLOCK 4

// ---------------- stage 1: trimmed-mean aggregation ----------------
// CRITICAL invariants (measured):
//  * node index must be blockIdx-derived (scalar) — threadIdx-derived i =>
//    ~10x VALU blowup (R6: 415us).
//  * SZ buckets must be powers of two — non-pow2 arrays trigger promote-to-LDS
//    + scratch spill (R8: LDS_Block=10240, 121k bank conflicts, 140us).
//  * 4-node sequential loop with unroll 1 — tests dispatch-rate hypothesis
//    (57us floor across R2/R7/R9 ≈ 7 cyc/workgroup chip-wide).

// Batcher odd-even mergesort network, ascending, fully unrolled.
// CE counts: SZ=4:5, 8:19, 16:63, 32:191.
template <int SZ>
__device__ __forceinline__ void oe_sort(float (&a)[SZ]) {
#pragma unroll
  for (int p = 1; p < SZ; p <<= 1) {
#pragma unroll
    for (int q = p; q >= 1; q >>= 1) {
#pragma unroll
      for (int j = q % p; j <= SZ - 1 - q; j += 2 * q) {
#pragma unroll
        for (int i = 0; i < q; ++i) {
          int x = i + j, y = i + j + q;
          if (y < SZ && (x / (2 * p)) == (y / (2 * p))) {
            float mn = fminf(a[x], a[y]);
            float mx = fmaxf(a[x], a[y]);
            a[x] = mn;
            a[y] = mx;
          }
        }
      }
    }
  }
}

// extract element at (block-uniform) position p from a statically-indexed register array
template <int SZ>
__device__ __forceinline__ float extract_pos(const float (&k)[SZ], int p) {
  float sel[SZ];
#pragma unroll
  for (int i = 0; i < SZ; ++i) sel[i] = k[i];
#pragma unroll
  for (int w = SZ >> 1; w >= 1; w >>= 1) {
    bool take = (p & w) != 0;  // p scalar -> uniform selects
#pragma unroll
    for (int i = 0; i < w; ++i) sel[i] = take ? sel[i + w] : sel[i];
  }
  return sel[0];
}

// Exact trimmed sum: payloads (key*norm_src) whose STABLE rank (key asc, ties
// by slot — matches jnp.argsort) lies in [b, n-b).
// Fast path: when sorted[b-1] < sorted[b] and sorted[n-b-1] < sorted[n-b],
// rank-membership == value-membership in [lo, hi] (exact, incl. lo==hi runs).
// Slow path (rare boundary ties): exact stable-rank scan.
template <int SZ>
__device__ __forceinline__ float trimmed_sum(const float* __restrict__ h,
                                             const float* __restrict__ norm,
                                             const int* __restrict__ nbr_row,
                                             int n, int f, int b) {
  float ko[SZ];
  float nrm[SZ];  // block-uniform -> SGPRs
#pragma unroll
  for (int d = 0; d < SZ; ++d) {
    if (d < n) {  // uniform branch (n block-uniform)
      int src = nbr_row[d];       // scalar load
      nrm[d] = norm[src];         // scalar load
      ko[d] = h[src * F + f];     // vector load, coalesced 256B/wave
    } else {
      nrm[d] = 0.f;
      ko[d] = FLT_MAX;            // pads sort past all valid keys
    }
  }

  float k[SZ];
#pragma unroll
  for (int d = 0; d < SZ; ++d) k[d] = ko[d];
  oe_sort<SZ>(k);

  const float lo  = extract_pos<SZ>(k, b);          // rank b (kept)
  const float hi  = extract_pos<SZ>(k, n - b - 1);  // rank n-b-1 (kept)
  const float lom = extract_pos<SZ>(k, b - 1);      // rank b-1 (trimmed)
  const float him = extract_pos<SZ>(k, n - b);      // rank n-b (trimmed)

  float sum = 0.f;
  if ((lom < lo) & (hi < him)) {
#pragma unroll
    for (int d = 0; d < SZ; ++d) {
      bool keep = (ko[d] >= lo) & (ko[d] <= hi);  // pads (FLT_MAX) fail
      sum = fmaf(keep ? ko[d] : 0.f, nrm[d], sum);
    }
  } else {
    int c_lt_lo = 0, c_lt_hi = 0;
#pragma unroll
    for (int d = 0; d < SZ; ++d) {
      c_lt_lo += (ko[d] < lo) ? 1 : 0;
      c_lt_hi += (ko[d] < hi) ? 1 : 0;
    }
    int run_lo = 0, run_hi = 0;
    const int nb = n - b;
#pragma unroll
    for (int d = 0; d < SZ; ++d) {
      const float kd = ko[d];
      const float m = kd * nrm[d];  // pads: FLT_MAX*0 = 0
      const bool eql = (kd == lo);
      const bool eqh = (kd == hi);
      const bool lh = (lo < hi);
      const bool btw = (kd > lo) & (kd < hi);
      const int r_lo = c_lt_lo + run_lo;  // stable rank if kd==lo
      const int r_hi = c_lt_hi + run_hi;  // stable rank if kd==hi
      const bool inc = btw
                     | (eql & (r_lo >= b) & (lh | (r_lo < nb)))
                     | (lh & eqh & (r_hi < nb));
      sum += inc ? m : 0.f;
      run_lo += eql ? 1 : 0;
      run_hi += eqh ? 1 : 0;
    }
  }
  return sum;
}

__global__ __launch_bounds__(128) void gcn_stage1(const float* __restrict__ h,
                                                  const float* __restrict__ norm,
                                                  const int* __restrict__ nbr,
                                                  const int* __restrict__ deg,
                                                  float* __restrict__ accum) {
  const int f = threadIdx.x;
#pragma unroll 1  // real loop: per-iteration working set = 1 node (no R5 spill)
  for (int it = 0; it < NODES_PER_BLOCK; ++it) {
    const int i = blockIdx.x * NODES_PER_BLOCK + it;  // blockIdx-derived: scalar
    const int n = deg[i];           // scalar
    const float ni = norm[i];
    const float hif = h[i * F + f];
    const int idx = i * F + f;

    if (n <= 3) {  // N_NEIGH_THRESHOLD branch (uniform; no barriers in kernel)
      accum[idx] = (float)n * hif * ni * ni;
      continue;
    }

    int b = n / 2 - (1 - (n & 1));
    int bcap = (int)floorf((float)n * 0.45f);
    b = b < bcap ? b : bcap;
    b = b > 1 ? b : 1;

    const int* nbr_row = nbr + i * MAXD;
    float ts;
    if (n <= 4)       ts = trimmed_sum<4>(h, norm, nbr_row, n, f, b);
    else if (n <= 8)  ts = trimmed_sum<8>(h, norm, nbr_row, n, f, b);
    else if (n <= 16) ts = trimmed_sum<16>(h, norm, nbr_row, n, f, b);
    else              ts = trimmed_sum<32>(h, norm, nbr_row, n, f, b);

    accum[idx] = (ts + hif * ni * (float)(2 * b)) * ni;
  }
}

// ---------------- stage 2: out = relu(accum @ W + bias) ----------------
// Round-8 verbatim (measured-by-subtraction ~18 us, non-spilling): 256 threads,
// 32 rows x 128 cols per block, k-chunk=32, 4x4 tile, k-quad b128 inner loop.
// kc loop `unroll 1` — full kc unroll spilled in round 5 (VGPR=256, 387MB scratch).
__global__ __launch_bounds__(256) void gcn_gemm(const float* __restrict__ A,
                                                const float* __restrict__ W,
                                                const float* __restrict__ bias,
                                                float* __restrict__ out) {
  __shared__ float Ws[32 * F];   // 16 KB: k-chunk of W, [k][c]
  __shared__ float As[32 * 36];  // 4.6 KB: [row][k], pad 36 keeps 16B align
  const int t = threadIdx.x;
  const int tx = t & 31;         // col group: cols tx*4..tx*4+3
  const int ty = t >> 5;         // row group: rows ty*4..ty*4+3
  const int row0 = blockIdx.x * 32;
  const int ar = t >> 3, ak = t & 7;  // A staging coords

  float acc[4][4];
#pragma unroll
  for (int r = 0; r < 4; ++r)
#pragma unroll
    for (int c = 0; c < 4; ++c) acc[r][c] = 0.f;

#pragma unroll 1
  for (int kc = 0; kc < F; kc += 32) {
    __syncthreads();  // protect As/Ws from previous chunk's readers
    // stage A: 32 rows x 32 k (1 float4/thread, coalesced)
    float4 av = *(const float4*)(A + (row0 + ar) * F + kc + ak * 4);
    *(float4*)(As + ar * 36 + ak * 4) = av;
    // stage W: 32 k x 128 c = 1024 float4 (4/thread, fully coalesced)
#pragma unroll
    for (int u = 0; u < 4; ++u) {
      int idx2 = u * 256 + t;
      *(float4*)(Ws + idx2 * 4) = *(const float4*)(W + kc * F + idx2 * 4);
    }
    __syncthreads();
#pragma unroll
    for (int kq = 0; kq < 8; ++kq) {
      float4 w0 = *(const float4*)(Ws + (kq * 4 + 0) * F + tx * 4);
      float4 w1 = *(const float4*)(Ws + (kq * 4 + 1) * F + tx * 4);
      float4 w2 = *(const float4*)(Ws + (kq * 4 + 2) * F + tx * 4);
      float4 w3 = *(const float4*)(Ws + (kq * 4 + 3) * F + tx * 4);
#pragma unroll
      for (int r = 0; r < 4; ++r) {
        float4 a = *(const float4*)(As + (ty * 4 + r) * 36 + kq * 4);  // broadcast
        acc[r][0] = fmaf(a.x, w0.x, acc[r][0]);
        acc[r][1] = fmaf(a.x, w0.y, acc[r][1]);
        acc[r][2] = fmaf(a.x, w0.z, acc[r][2]);
        acc[r][3] = fmaf(a.x, w0.w, acc[r][3]);
        acc[r][0] = fmaf(a.y, w1.x, acc[r][0]);
        acc[r][1] = fmaf(a.y, w1.y, acc[r][1]);
        acc[r][2] = fmaf(a.y, w1.z, acc[r][2]);
        acc[r][3] = fmaf(a.y, w1.w, acc[r][3]);
        acc[r][0] = fmaf(a.z, w2.x, acc[r][0]);
        acc[r][1] = fmaf(a.z, w2.y, acc[r][1]);
        acc[r][2] = fmaf(a.z, w2.z, acc[r][2]);
        acc[r][3] = fmaf(a.z, w2.w, acc[r][3]);
        acc[r][0] = fmaf(a.w, w3.x, acc[r][0]);
        acc[r][1] = fmaf(a.w, w3.y, acc[r][1]);
        acc[r][2] = fmaf(a.w, w3.z, acc[r][2]);
        acc[r][3] = fmaf(a.w, w3.w, acc[r][3]);
      }
    }
  }

  float4 bv = *(const float4*)(bias + tx * 4);
#pragma unroll
  for (int r = 0; r < 4; ++r) {
    float4 o;
    o.x = fmaxf(acc[r][0] + bv.x, 0.f);
    o.y = fmaxf(acc[r][1] + bv.y, 0.f);
    o.z = fmaxf(acc[r][2] + bv.z, 0.f);
    o.w = fmaxf(acc[r][3] + bv.w, 0.f);
    *(float4*)(out + (row0 + ty * 4 + r) * F + tx * 4) = o;
  }
}

extern "C" void kernel_launch(void* const* d_in, const int* in_sizes, int n_in,
                              void* d_out, int out_size, void* d_ws, size_t ws_size,
                              hipStream_t stream) {
  const float* h = (const float*)d_in[0];
  const float* norm = (const float*)d_in[1];
  const float* weight = (const float*)d_in[2];
  const float* bias = (const float*)d_in[3];
  const int* nbr = (const int*)d_in[4];
  const int* deg = (const int*)d_in[5];
  float* out = (float*)d_out;
  float* accum = (float*)d_ws;  // 20000*128*4 = 10.24 MB scratch

  gcn_stage1<<<N_NODES / NODES_PER_BLOCK, 128, 0, stream>>>(h, norm, nbr, deg, accum);
  gcn_gemm<<<N_NODES / 32, 256, 0, stream>>>(accum, weight, bias, out);
}

// Round 11
// 116.008 us; speedup vs baseline: 1.1892x; 1.1892x over previous
//
#include <hip/hip_runtime.h>
#include <cfloat>
#include <cmath>

#define N_NODES 20000
#define MAXD 32
#define F 128

// ---------------- stage 1: trimmed-mean aggregation ----------------
// CRITICAL invariants (measured):
//  * node index must be blockIdx-derived (scalar) — threadIdx-derived i =>
//    ~10x VALU blowup (R6: 415us).
//  * private arrays must be pow2-sized with static indices — non-pow2 triggers
//    promote-to-LDS + scratch spill (R8: LDS_Block=10240, 140us).
//  * 1 node / 128-thread block (R9: 57us). 4-node loop regressed (R10: 61-64us);
//    dispatch rate and occupancy are NOT the limiter — VALU inst count is.
// This round: exact-n templates. b = f(n) is compile-time, so the 4 extract
// positions are direct register reads (kills 124 cndmask at SZ32), and the
// sort network is pruned via the pad invariant: positions >= n hold FLT_MAX
// throughout an ascending network (induction: max-output at y>=n stays MAX,
// min-output unchanged), so comparators with y >= n are no-ops and are skipped
// at compile time.

// Batcher odd-even mergesort network, ascending, fully unrolled, pruned to the
// first NV lanes (NV <= SZ). NV==SZ reproduces the full network.
template <int SZ, int NV>
__device__ __forceinline__ void oe_sort_n(float (&a)[SZ]) {
#pragma unroll
  for (int p = 1; p < SZ; p <<= 1) {
#pragma unroll
    for (int q = p; q >= 1; q >>= 1) {
#pragma unroll
      for (int j = q % p; j <= SZ - 1 - q; j += 2 * q) {
#pragma unroll
        for (int i = 0; i < q; ++i) {
          int x = i + j, y = i + j + q;
          if (y < NV && (x / (2 * p)) == (y / (2 * p))) {  // y<NV ⊆ y<SZ
            float mn = fminf(a[x], a[y]);
            float mx = fmaxf(a[x], a[y]);
            a[x] = mn;
            a[y] = mx;
          }
        }
      }
    }
  }
}

// b = max(min(n/2 - (1-n%2), (int)floor_f32(n*0.45f)), 1) — f32 mult matches
// jnp exactly (e.g. n=20: 20*0.449999988f = 8.9999998 -> 8, not 9).
template <int N>
struct TrimB {
  static constexpr int b_raw = N / 2 - (1 - (N & 1));
  static constexpr int b_cap = (int)((float)N * 0.45f);  // trunc == floor (pos)
  static constexpr int b_min = b_raw < b_cap ? b_raw : b_cap;
  static constexpr int value = b_min > 1 ? b_min : 1;
};

// Exact trimmed sum, exact-n specialization. Stable-rank semantics match
// jnp.argsort (ties by slot). Fast path: no equal-key run straddles either
// trim boundary -> pure value test. Slow path (rare): exact stable-rank scan.
template <int SZ, int N>
__device__ __forceinline__ float trimmed_sum_n(const float* __restrict__ h,
                                               const float* __restrict__ norm,
                                               const int* __restrict__ nbr_row,
                                               int f) {
  constexpr int B = TrimB<N>::value;
  constexpr int NB = N - B;

  float ko[SZ];
  float nrm[SZ];  // block-uniform -> SGPRs
  float k[SZ];
#pragma unroll
  for (int d = 0; d < N; ++d) {
    int src = nbr_row[d];       // scalar load
    nrm[d] = norm[src];         // scalar load
    ko[d] = h[src * F + f];     // vector load, coalesced 256B/wave
    k[d] = ko[d];
  }
#pragma unroll
  for (int d = N; d < SZ; ++d) k[d] = FLT_MAX;  // pads sort past all valid keys

  oe_sort_n<SZ, N>(k);

  const float lo  = k[B];       // rank B (kept)      — direct register reads,
  const float hi  = k[NB - 1];  // rank N-B-1 (kept)    positions compile-time
  const float lom = k[B - 1];   // rank B-1 (trimmed)
  const float him = k[NB];      // rank N-B (trimmed); NB <= N-1 < N valid

  float sum = 0.f;
  if ((lom < lo) & (hi < him)) {
#pragma unroll
    for (int d = 0; d < N; ++d) {
      bool keep = (ko[d] >= lo) & (ko[d] <= hi);
      sum = fmaf(keep ? ko[d] : 0.f, nrm[d], sum);
    }
  } else {
    int c_lt_lo = 0, c_lt_hi = 0;
#pragma unroll
    for (int d = 0; d < N; ++d) {
      c_lt_lo += (ko[d] < lo) ? 1 : 0;
      c_lt_hi += (ko[d] < hi) ? 1 : 0;
    }
    int run_lo = 0, run_hi = 0;
#pragma unroll
    for (int d = 0; d < N; ++d) {
      const float kd = ko[d];
      const float m = kd * nrm[d];
      const bool eql = (kd == lo);
      const bool eqh = (kd == hi);
      const bool lh = (lo < hi);
      const bool btw = (kd > lo) & (kd < hi);
      const int r_lo = c_lt_lo + run_lo;  // stable rank if kd==lo
      const int r_hi = c_lt_hi + run_hi;  // stable rank if kd==hi
      const bool inc = btw
                     | (eql & (r_lo >= B) & (lh | (r_lo < NB)))
                     | (lh & eqh & (r_hi < NB));
      sum += inc ? m : 0.f;
      run_lo += eql ? 1 : 0;
      run_hi += eqh ? 1 : 0;
    }
  }
  return sum;
}

__global__ __launch_bounds__(128) void gcn_stage1(const float* __restrict__ h,
                                                  const float* __restrict__ norm,
                                                  const int* __restrict__ nbr,
                                                  const int* __restrict__ deg,
                                                  float* __restrict__ accum) {
  const int i = blockIdx.x;       // MUST stay blockIdx-derived (scalar)
  const int f = threadIdx.x;
  const int n = deg[i];           // scalar
  const float ni = norm[i];
  const float hif = h[i * F + f];
  const int idx = i * F + f;

  if (n <= 3) {  // N_NEIGH_THRESHOLD branch
    accum[idx] = (float)n * hif * ni * ni;
    return;
  }

  const int* nbr_row = nbr + i * MAXD;
  float ts;
  int b;
  switch (n) {  // scalar switch; each case fully compile-time specialized
#define TS_CASE(NN, SS) \
    case NN: ts = trimmed_sum_n<SS, NN>(h, norm, nbr_row, f); b = TrimB<NN>::value; break;
    TS_CASE(4, 4)
    TS_CASE(5, 8) TS_CASE(6, 8) TS_CASE(7, 8) TS_CASE(8, 8)
    TS_CASE(9, 16) TS_CASE(10, 16) TS_CASE(11, 16) TS_CASE(12, 16)
    TS_CASE(13, 16) TS_CASE(14, 16) TS_CASE(15, 16) TS_CASE(16, 16)
    TS_CASE(17, 32) TS_CASE(18, 32) TS_CASE(19, 32) TS_CASE(20, 32)
    TS_CASE(21, 32) TS_CASE(22, 32) TS_CASE(23, 32) TS_CASE(24, 32)
    TS_CASE(25, 32) TS_CASE(26, 32) TS_CASE(27, 32) TS_CASE(28, 32)
    TS_CASE(29, 32) TS_CASE(30, 32) TS_CASE(31, 32)
    default: ts = trimmed_sum_n<32, 32>(h, norm, nbr_row, f); b = TrimB<32>::value; break;
#undef TS_CASE
  }

  accum[idx] = (ts + hif * ni * (float)(2 * b)) * ni;
}

// ---------------- stage 2: out = relu(accum @ W + bias) ----------------
// Round-8 verbatim (measured-by-subtraction ~18 us, non-spilling): 256 threads,
// 32 rows x 128 cols per block, k-chunk=32, 4x4 tile, k-quad b128 inner loop.
// kc loop `unroll 1` — full kc unroll spilled in round 5 (VGPR=256, 387MB scratch).
__global__ __launch_bounds__(256) void gcn_gemm(const float* __restrict__ A,
                                                const float* __restrict__ W,
                                                const float* __restrict__ bias,
                                                float* __restrict__ out) {
  __shared__ float Ws[32 * F];   // 16 KB: k-chunk of W, [k][c]
  __shared__ float As[32 * 36];  // 4.6 KB: [row][k], pad 36 keeps 16B align
  const int t = threadIdx.x;
  const int tx = t & 31;         // col group: cols tx*4..tx*4+3
  const int ty = t >> 5;         // row group: rows ty*4..ty*4+3
  const int row0 = blockIdx.x * 32;
  const int ar = t >> 3, ak = t & 7;  // A staging coords

  float acc[4][4];
#pragma unroll
  for (int r = 0; r < 4; ++r)
#pragma unroll
    for (int c = 0; c < 4; ++c) acc[r][c] = 0.f;

#pragma unroll 1
  for (int kc = 0; kc < F; kc += 32) {
    __syncthreads();  // protect As/Ws from previous chunk's readers
    // stage A: 32 rows x 32 k (1 float4/thread, coalesced)
    float4 av = *(const float4*)(A + (row0 + ar) * F + kc + ak * 4);
    *(float4*)(As + ar * 36 + ak * 4) = av;
    // stage W: 32 k x 128 c = 1024 float4 (4/thread, fully coalesced)
#pragma unroll
    for (int u = 0; u < 4; ++u) {
      int idx2 = u * 256 + t;
      *(float4*)(Ws + idx2 * 4) = *(const float4*)(W + kc * F + idx2 * 4);
    }
    __syncthreads();
#pragma unroll
    for (int kq = 0; kq < 8; ++kq) {
      float4 w0 = *(const float4*)(Ws + (kq * 4 + 0) * F + tx * 4);
      float4 w1 = *(const float4*)(Ws + (kq * 4 + 1) * F + tx * 4);
      float4 w2 = *(const float4*)(Ws + (kq * 4 + 2) * F + tx * 4);
      float4 w3 = *(const float4*)(Ws + (kq * 4 + 3) * F + tx * 4);
#pragma unroll
      for (int r = 0; r < 4; ++r) {
        float4 a = *(const float4*)(As + (ty * 4 + r) * 36 + kq * 4);  // broadcast
        acc[r][0] = fmaf(a.x, w0.x, acc[r][0]);
        acc[r][1] = fmaf(a.x, w0.y, acc[r][1]);
        acc[r][2] = fmaf(a.x, w0.z, acc[r][2]);
        acc[r][3] = fmaf(a.x, w0.w, acc[r][3]);
        acc[r][0] = fmaf(a.y, w1.x, acc[r][0]);
        acc[r][1] = fmaf(a.y, w1.y, acc[r][1]);
        acc[r][2] = fmaf(a.y, w1.z, acc[r][2]);
        acc[r][3] = fmaf(a.y, w1.w, acc[r][3]);
        acc[r][0] = fmaf(a.z, w2.x, acc[r][0]);
        acc[r][1] = fmaf(a.z, w2.y, acc[r][1]);
        acc[r][2] = fmaf(a.z, w2.z, acc[r][2]);
        acc[r][3] = fmaf(a.z, w2.w, acc[r][3]);
        acc[r][0] = fmaf(a.w, w3.x, acc[r][0]);
        acc[r][1] = fmaf(a.w, w3.y, acc[r][1]);
        acc[r][2] = fmaf(a.w, w3.z, acc[r][2]);
        acc[r][3] = fmaf(a.w, w3.w, acc[r][3]);
      }
    }
  }

  float4 bv = *(const float4*)(bias + tx * 4);
#pragma unroll
  for (int r = 0; r < 4; ++r) {
    float4 o;
    o.x = fmaxf(acc[r][0] + bv.x, 0.f);
    o.y = fmaxf(acc[r][1] + bv.y, 0.f);
    o.z = fmaxf(acc[r][2] + bv.z, 0.f);
    o.w = fmaxf(acc[r][3] + bv.w, 0.f);
    *(float4*)(out + (row0 + ty * 4 + r) * F + tx * 4) = o;
  }
}

extern "C" void kernel_launch(void* const* d_in, const int* in_sizes, int n_in,
                              void* d_out, int out_size, void* d_ws, size_t ws_size,
                              hipStream_t stream) {
  const float* h = (const float*)d_in[0];
  const float* norm = (const float*)d_in[1];
  const float* weight = (const float*)d_in[2];
  const float* bias = (const float*)d_in[3];
  const int* nbr = (const int*)d_in[4];
  const int* deg = (const int*)d_in[5];
  float* out = (float*)d_out;
  float* accum = (float*)d_ws;  // 20000*128*4 = 10.24 MB scratch

  gcn_stage1<<<N_NODES, 128, 0, stream>>>(h, norm, nbr, deg, accum);
  gcn_gemm<<<N_NODES / 32, 256, 0, stream>>>(accum, weight, bias, out);
}